// Round 12
// baseline (79.660 us; speedup 1.0000x reference)
//
#include <hip/hip_runtime.h>

// UpsampleFlow2: Gaussian Nadaraya-Watson upsampling.
// out [B,3,N] = (sum_s k*f)/(sum_s k), k = exp(-|x-y|^2/r^2).
// exp(-|x|^2/r^2) cancels in num/den ->
//   k' = exp2( fma(px,ax, fma(py,ay, fma(pz,az, bias))) )
//   a = c2*y, bias = cy*|y|^2, c2=2*log2e/r^2, cy=-log2e/r^2.
//
// R12: REPLACE v_exp_f32 WITH PACKED POLYNOMIAL. Evidence chain:
//  - R11 decomposition: launch+combine+gap ~ 0.5us; staging/write ~3.2us;
//    in-dispatch constant K ~ 13.6us (structure-invariant, unattackable);
//    inner ~13.9us is the remaining lever.
//  - R9: halving fma issue via pk = NULL -> inner is NOT fma-bound.
//  - Only consistent model: v_exp_f32 occupies VALU ~28-30cyc/wave64.
// Fix: 2^e = ldexp(P6(e-floor(e)), (int)floor(e)), Cephes exp2f poly
// (rel err ~1e-8). Poly is plain pipelined VALU, packed over SPARSE PAIRS
// (R6 pair-packed LDS layout): ~21-23 cyc/pair vs 30.
// Config = R8 (SC=16, 256 blocks, PPT=8) to isolate the exp->poly delta.

typedef float v2f __attribute__((ext_vector_type(2)));

constexpr int B_ = 4, N_ = 8192, S_ = 2048;
constexpr int BLOCK = 256, PPT = 8;
constexpr int PTS_PER_BLOCK = BLOCK * PPT;      // 2048
constexpr int NBPB = N_ / PTS_PER_BLOCK;        // 4
constexpr int NB = B_ * NBPB;                   // 16
constexpr int BN = B_ * N_;                     // 32768
constexpr float LOG2E = 1.4426950408889634f;

// Cephes exp2f polynomial: 2^f = 1 + f*P(f), f in [0,1)
constexpr float C5 = 1.535336188319500e-4f;
constexpr float C4 = 1.339887440266574e-3f;
constexpr float C3 = 9.618437357674640e-3f;
constexpr float C2 = 5.550332471162809e-2f;
constexpr float C1 = 2.402264791363012e-1f;
constexpr float C0 = 6.931472028550421e-1f;

#define PK_FMA(d, a, b, c) \
    asm("v_pk_fma_f32 %0, %1, %2, %3" : "=v"(d) : "v"(a), "v"(b), "v"(c))
#define PK_FMA_ACC(acc, a, b) \
    asm("v_pk_fma_f32 %0, %1, %2, %0" : "+v"(acc) : "v"(a), "v"(b))
#define PK_ADD_ACC(acc, a) \
    asm("v_pk_add_f32 %0, %1, %0" : "+v"(acc) : "v"(a))

template <int CHUNK>
__global__ __launch_bounds__(BLOCK, 4) void uf2_main(
    const float* __restrict__ xyz,
    const float* __restrict__ sxyz,
    const float* __restrict__ sflow,
    const int* __restrict__ resol,
    float4* __restrict__ part)
{
    constexpr int TP = CHUNK / 2;      // sparse pairs per chunk
    __shared__ float4 AXY[TP];         // (ax0, ax1, ay0, ay1)
    __shared__ float4 AZW[TP];         // (az0, az1, bias0, bias1)
    __shared__ float4 FXY[TP];         // (fx0, fx1, fy0, fy1)
    __shared__ v2f    FZ2[TP];         // (fz0, fz1)

    const int nb = blockIdx.x % NB;
    const int sc = blockIdx.x / NB;
    const int b  = nb / NBPB;
    const int n0 = (nb % NBPB) * PTS_PER_BLOCK;
    const int s0 = sc * CHUNK;

    const float r = (float)resol[0];            // INITIAL_RADIUS(=1)*resol
    const float inv_r2 = 1.0f / (r * r);
    const float c2 = 2.0f * inv_r2 * LOG2E;
    const float cy = -inv_r2 * LOG2E;

    // ---- stage sparse chunk, pair-packed for pk consumption ----
    const float* yb = sxyz  + b * 3 * S_;
    const float* fb = sflow + b * 3 * S_;
    for (int tp = threadIdx.x; tp < TP; tp += BLOCK) {
        const int s = s0 + 2 * tp;
        const float yx0 = yb[s],          yx1 = yb[s + 1];
        const float yy0 = yb[S_ + s],     yy1 = yb[S_ + s + 1];
        const float yz0 = yb[2 * S_ + s], yz1 = yb[2 * S_ + s + 1];
        const float fx0 = fb[s],          fx1 = fb[s + 1];
        const float fy0 = fb[S_ + s],     fy1 = fb[S_ + s + 1];
        const float fz0 = fb[2 * S_ + s], fz1 = fb[2 * S_ + s + 1];
        AXY[tp] = make_float4(c2 * yx0, c2 * yx1, c2 * yy0, c2 * yy1);
        AZW[tp] = make_float4(c2 * yz0, c2 * yz1,
                              cy * (yx0 * yx0 + yy0 * yy0 + yz0 * yz0),
                              cy * (yx1 * yx1 + yy1 * yy1 + yz1 * yz1));
        FXY[tp] = make_float4(fx0, fx1, fy0, fy1);
        FZ2[tp] = (v2f){fz0, fz1};
    }
    __syncthreads();

    // ---- per-thread query points, splatted once (loop-invariant) ----
    const float* xb = xyz + b * 3 * N_;
    v2f px2[PPT], py2[PPT], pz2[PPT];
    v2f acx[PPT], acy[PPT], acz[PPT], acw[PPT];
#pragma unroll
    for (int p = 0; p < PPT; ++p) {
        const int n = n0 + threadIdx.x + p * BLOCK;
        const float x = xb[n], y = xb[N_ + n], z = xb[2 * N_ + n];
        px2[p] = (v2f){x, x}; py2[p] = (v2f){y, y}; pz2[p] = (v2f){z, z};
        acx[p] = (v2f){0.f, 0.f}; acy[p] = (v2f){0.f, 0.f};
        acz[p] = (v2f){0.f, 0.f}; acw[p] = (v2f){0.f, 0.f};
    }

    const v2f c52 = (v2f){C5, C5}, c42 = (v2f){C4, C4}, c32 = (v2f){C3, C3};
    const v2f c22 = (v2f){C2, C2}, c12 = (v2f){C1, C1}, c02 = (v2f){C0, C0};
    const v2f one2 = (v2f){1.0f, 1.0f};

    // ---- main loop: poly-exp2, packed over sparse pairs ----
#pragma unroll 2
    for (int tp = 0; tp < TP; ++tp) {
        const float4 a1 = AXY[tp];     // broadcast ds_read_b128
        const float4 a2 = AZW[tp];
        const float4 f1 = FXY[tp];
        const v2f    fz2 = FZ2[tp];
        const v2f ax2 = (v2f){a1.x, a1.y}, ay2 = (v2f){a1.z, a1.w};
        const v2f az2 = (v2f){a2.x, a2.y}, bi2 = (v2f){a2.z, a2.w};
        const v2f fx2 = (v2f){f1.x, f1.y}, fy2 = (v2f){f1.z, f1.w};
#pragma unroll
        for (int p = 0; p < PPT; ++p) {
            // e2 = c2*dot(x,y) + cy*|y|^2  (packed over 2 sparse pts)
            v2f e2;
            PK_FMA(e2, pz2[p], az2, bi2);
            PK_FMA_ACC(e2, py2[p], ay2);
            PK_FMA_ACC(e2, px2[p], ax2);
            // 2^e = ldexp(1 + f*P(f), floor(e)),  f = e - floor(e)
            const float fl0 = floorf(e2.x), fl1 = floorf(e2.y);
            const v2f fl2 = (v2f){fl0, fl1};
            const v2f f2 = e2 - fl2;              // v_pk_add (neg)
            const int i0 = (int)fl0, i1 = (int)fl1;
            v2f pp;
            PK_FMA(pp, c52, f2, c42);
            PK_FMA(pp, pp, f2, c32);
            PK_FMA(pp, pp, f2, c22);
            PK_FMA(pp, pp, f2, c12);
            PK_FMA(pp, pp, f2, c02);
            v2f k2;
            PK_FMA(k2, pp, f2, one2);             // 1 + f*P(f)
            const float k0 = ldexpf(k2.x, i0);
            const float k1 = ldexpf(k2.y, i1);
            const v2f kk = (v2f){k0, k1};
            PK_FMA_ACC(acx[p], kk, fx2);
            PK_FMA_ACC(acy[p], kk, fy2);
            PK_FMA_ACC(acz[p], kk, fz2);
            PK_ADD_ACC(acw[p], kk);
        }
    }

    // ---- reduce s-halves, write partials (coalesced float4) ----
#pragma unroll
    for (int p = 0; p < PPT; ++p) {
        const int g = b * N_ + n0 + threadIdx.x + p * BLOCK;
        part[(size_t)sc * BN + g] = make_float4(
            acx[p].x + acx[p].y, acy[p].x + acy[p].y,
            acz[p].x + acz[p].y, acw[p].x + acw[p].y);
    }
}

__global__ __launch_bounds__(BLOCK) void uf2_combine(
    const float4* __restrict__ part, float* __restrict__ out, int SC)
{
    const int g = blockIdx.x * BLOCK + threadIdx.x;   // 0..BN-1
    float4 s0 = make_float4(0.f, 0.f, 0.f, 0.f);
    float4 s1 = s0, s2 = s0, s3 = s0;
    int c = 0;
    for (; c + 4 <= SC; c += 4) {
        const float4 p0 = part[(size_t)(c + 0) * BN + g];
        const float4 p1 = part[(size_t)(c + 1) * BN + g];
        const float4 p2 = part[(size_t)(c + 2) * BN + g];
        const float4 p3 = part[(size_t)(c + 3) * BN + g];
        s0.x += p0.x; s0.y += p0.y; s0.z += p0.z; s0.w += p0.w;
        s1.x += p1.x; s1.y += p1.y; s1.z += p1.z; s1.w += p1.w;
        s2.x += p2.x; s2.y += p2.y; s2.z += p2.z; s2.w += p2.w;
        s3.x += p3.x; s3.y += p3.y; s3.z += p3.z; s3.w += p3.w;
    }
    for (; c < SC; ++c) {
        const float4 p = part[(size_t)c * BN + g];
        s0.x += p.x; s0.y += p.y; s0.z += p.z; s0.w += p.w;
    }
    const float sx = (s0.x + s1.x) + (s2.x + s3.x);
    const float sy = (s0.y + s1.y) + (s2.y + s3.y);
    const float sz = (s0.z + s1.z) + (s2.z + s3.z);
    const float sw = (s0.w + s1.w) + (s2.w + s3.w);
    const float inv = 1.0f / sw;
    const int b = g >> 13;            // /8192
    const int n = g & (N_ - 1);
    float* ob = out + b * 3 * N_;
    ob[n]          = sx * inv;
    ob[N_ + n]     = sy * inv;
    ob[2 * N_ + n] = sz * inv;
}

// Fallback (ws too small): single kernel, full S staged in LDS, direct out.
__global__ __launch_bounds__(BLOCK, 1) void uf2_fused(
    const float* __restrict__ xyz,
    const float* __restrict__ sxyz,
    const float* __restrict__ sflow,
    const int* __restrict__ resol,
    float* __restrict__ out)
{
    constexpr int FPPT = 4;
    constexpr int PTS = BLOCK * FPPT;
    __shared__ float4 As[S_];
    __shared__ float4 Fs[S_];

    const int nb = blockIdx.x;
    const int b  = nb / (N_ / PTS);
    const int n0 = (nb % (N_ / PTS)) * PTS;

    const float r = (float)resol[0];
    const float inv_r2 = 1.0f / (r * r);
    const float c2 = 2.0f * inv_r2 * LOG2E;
    const float cy = -inv_r2 * LOG2E;

    const float* yb = sxyz  + b * 3 * S_;
    const float* fb = sflow + b * 3 * S_;
    for (int t = threadIdx.x; t < S_; t += BLOCK) {
        const float yx = yb[t], yy = yb[S_ + t], yz = yb[2 * S_ + t];
        const float fx = fb[t], fy = fb[S_ + t], fz = fb[2 * S_ + t];
        As[t] = make_float4(c2 * yx, c2 * yy, c2 * yz,
                            cy * (yx * yx + yy * yy + yz * yz));
        Fs[t] = make_float4(fx, fy, fz, 0.0f);
    }
    __syncthreads();

    const float* xb = xyz + b * 3 * N_;
    float px[FPPT], py[FPPT], pz[FPPT];
    float4 acc[FPPT];
#pragma unroll
    for (int p = 0; p < FPPT; ++p) {
        const int n = n0 + threadIdx.x + p * BLOCK;
        px[p] = xb[n]; py[p] = xb[N_ + n]; pz[p] = xb[2 * N_ + n];
        acc[p] = make_float4(0.f, 0.f, 0.f, 0.f);
    }
#pragma unroll 4
    for (int t = 0; t < S_; ++t) {
        const float4 a = As[t];
        const float4 f = Fs[t];
#pragma unroll
        for (int p = 0; p < FPPT; ++p) {
            float e = fmaf(pz[p], a.z, a.w);
            e = fmaf(py[p], a.y, e);
            e = fmaf(px[p], a.x, e);
            const float k = __builtin_amdgcn_exp2f(e);
            acc[p].x = fmaf(k, f.x, acc[p].x);
            acc[p].y = fmaf(k, f.y, acc[p].y);
            acc[p].z = fmaf(k, f.z, acc[p].z);
            acc[p].w += k;
        }
    }
#pragma unroll
    for (int p = 0; p < FPPT; ++p) {
        const int n = n0 + threadIdx.x + p * BLOCK;
        const float inv = 1.0f / acc[p].w;
        float* ob = out + b * 3 * N_;
        ob[n]          = acc[p].x * inv;
        ob[N_ + n]     = acc[p].y * inv;
        ob[2 * N_ + n] = acc[p].z * inv;
    }
}

extern "C" void kernel_launch(void* const* d_in, const int* in_sizes, int n_in,
                              void* d_out, int out_size, void* d_ws, size_t ws_size,
                              hipStream_t stream)
{
    const float* xyz   = (const float*)d_in[0];
    const float* sxyz  = (const float*)d_in[1];
    const float* sflow = (const float*)d_in[2];
    const int*   resol = (const int*)d_in[3];
    float* out = (float*)d_out;
    float4* part = (float4*)d_ws;

    const size_t per_chunk = (size_t)BN * sizeof(float4);   // 512 KB
    int SC = 16;
    while (SC > 1 && (size_t)SC * per_chunk > ws_size) SC >>= 1;

    if ((size_t)SC * per_chunk > ws_size) {
        uf2_fused<<<dim3(BN / 1024), dim3(BLOCK), 0, stream>>>(
            xyz, sxyz, sflow, resol, out);
        return;
    }

    dim3 grid(NB * SC), blk(BLOCK);
    switch (SC) {
        case 16: uf2_main<S_ / 16><<<grid, blk, 0, stream>>>(xyz, sxyz, sflow, resol, part); break;
        case 8:  uf2_main<S_ / 8 ><<<grid, blk, 0, stream>>>(xyz, sxyz, sflow, resol, part); break;
        case 4:  uf2_main<S_ / 4 ><<<grid, blk, 0, stream>>>(xyz, sxyz, sflow, resol, part); break;
        case 2:  uf2_main<S_ / 2 ><<<grid, blk, 0, stream>>>(xyz, sxyz, sflow, resol, part); break;
        default: uf2_main<S_     ><<<grid, blk, 0, stream>>>(xyz, sxyz, sflow, resol, part); break;
    }
    uf2_combine<<<dim3(BN / BLOCK), dim3(BLOCK), 0, stream>>>(part, out, SC);
}

// Round 13
// 39.627 us; speedup vs baseline: 2.0102x; 2.0102x over previous
//
#include <hip/hip_runtime.h>

// UpsampleFlow2: Gaussian Nadaraya-Watson upsampling.
// out [B,3,N] = (sum_s k*f)/(sum_s k), k = exp(-|x-y|^2/r^2).
// exp(-|x|^2/r^2) cancels in num/den ->
//   k' = exp2( fma(px,ax, fma(py,ay, fma(pz,az, bias))) )
//   a = c2*y, bias = cy*|y|^2, c2=2*log2e/r^2, cy=-log2e/r^2.
//
// R13: R12's poly retried WITHOUT the register spill. R12 post-mortem:
// __launch_bounds__(...,4) capped VGPR=64 < ~150 needed -> scratch spill
// (FETCH 594KB->4MB, VALUBusy 88->21%). Fix: bounds (256,2).
// exp2 via rint-trick + deg-4 Taylor, pk-packed over sparse pairs:
//   t = e + 12582912.0 ; i = as_int(t)-0x4B400000 ; fl = t-C ; f = e-fl
//   2^e = ldexp(1 + f*P3(f), i),  f in [-0.5,0.5], rel err ~4e-5.
// 14 pk + 4 scalar per 2 pairs = 18 cyc/pair vs measured 28.7 (v_exp_f32
// serializes ~16cyc/wave64 with VALU; R9 pk-dot null proved fma not the
// bottleneck). Config = R8 minimal-traffic: SC=16, 256 blocks, PPT=8.

typedef float v2f __attribute__((ext_vector_type(2)));

constexpr int B_ = 4, N_ = 8192, S_ = 2048;
constexpr int BLOCK = 256, PPT = 8;
constexpr int PTS_PER_BLOCK = BLOCK * PPT;      // 2048
constexpr int NBPB = N_ / PTS_PER_BLOCK;        // 4
constexpr int NB = B_ * NBPB;                   // 16
constexpr int BN = B_ * N_;                     // 32768
constexpr float LOG2E = 1.4426950408889634f;

// Taylor of 2^f = 1 + f*(c1 + f*(c2 + f*(c3 + f*c4))), f in [-0.5, 0.5]
constexpr float T1 = 0.6931471805599453f;
constexpr float T2 = 0.2402265069591007f;
constexpr float T3 = 0.0555041086648216f;
constexpr float T4 = 0.0096181291076285f;
constexpr float RINT_C = 12582912.0f;           // 2^23 + 2^22
constexpr int   RINT_I = 0x4B400000;

#define PK_FMA(d, a, b, c) \
    asm("v_pk_fma_f32 %0, %1, %2, %3" : "=v"(d) : "v"(a), "v"(b), "v"(c))
#define PK_FMA_ACC(acc, a, b) \
    asm("v_pk_fma_f32 %0, %1, %2, %0" : "+v"(acc) : "v"(a), "v"(b))
#define PK_HORNER(p_, f_, c_) \
    asm("v_pk_fma_f32 %0, %0, %1, %2" : "+v"(p_) : "v"(f_), "v"(c_))
#define PK_ADD(d, a, b) \
    asm("v_pk_add_f32 %0, %1, %2" : "=v"(d) : "v"(a), "v"(b))
#define PK_ADD_ACC(acc, a) \
    asm("v_pk_add_f32 %0, %1, %0" : "+v"(acc) : "v"(a))

template <int CHUNK>
__global__ __launch_bounds__(BLOCK, 2) void uf2_main(
    const float* __restrict__ xyz,
    const float* __restrict__ sxyz,
    const float* __restrict__ sflow,
    const int* __restrict__ resol,
    float4* __restrict__ part)
{
    constexpr int TP = CHUNK / 2;      // sparse pairs per chunk
    __shared__ float4 AXY[TP];         // (ax0, ax1, ay0, ay1)
    __shared__ float4 AZW[TP];         // (az0, az1, bias0, bias1)
    __shared__ float4 FXY[TP];         // (fx0, fx1, fy0, fy1)
    __shared__ v2f    FZ2[TP];         // (fz0, fz1)

    const int nb = blockIdx.x % NB;
    const int sc = blockIdx.x / NB;
    const int b  = nb / NBPB;
    const int n0 = (nb % NBPB) * PTS_PER_BLOCK;
    const int s0 = sc * CHUNK;

    const float r = (float)resol[0];            // INITIAL_RADIUS(=1)*resol
    const float inv_r2 = 1.0f / (r * r);
    const float c2 = 2.0f * inv_r2 * LOG2E;
    const float cy = -inv_r2 * LOG2E;

    // ---- stage sparse chunk, pair-packed for pk consumption ----
    const float* yb = sxyz  + b * 3 * S_;
    const float* fb = sflow + b * 3 * S_;
    for (int tp = threadIdx.x; tp < TP; tp += BLOCK) {
        const int s = s0 + 2 * tp;
        const float yx0 = yb[s],          yx1 = yb[s + 1];
        const float yy0 = yb[S_ + s],     yy1 = yb[S_ + s + 1];
        const float yz0 = yb[2 * S_ + s], yz1 = yb[2 * S_ + s + 1];
        const float fx0 = fb[s],          fx1 = fb[s + 1];
        const float fy0 = fb[S_ + s],     fy1 = fb[S_ + s + 1];
        const float fz0 = fb[2 * S_ + s], fz1 = fb[2 * S_ + s + 1];
        AXY[tp] = make_float4(c2 * yx0, c2 * yx1, c2 * yy0, c2 * yy1);
        AZW[tp] = make_float4(c2 * yz0, c2 * yz1,
                              cy * (yx0 * yx0 + yy0 * yy0 + yz0 * yz0),
                              cy * (yx1 * yx1 + yy1 * yy1 + yz1 * yz1));
        FXY[tp] = make_float4(fx0, fx1, fy0, fy1);
        FZ2[tp] = (v2f){fz0, fz1};
    }
    __syncthreads();

    // ---- per-thread query points, splatted once (loop-invariant) ----
    const float* xb = xyz + b * 3 * N_;
    v2f px2[PPT], py2[PPT], pz2[PPT];
    v2f acx[PPT], acy[PPT], acz[PPT], acw[PPT];
#pragma unroll
    for (int p = 0; p < PPT; ++p) {
        const int n = n0 + threadIdx.x + p * BLOCK;
        const float x = xb[n], y = xb[N_ + n], z = xb[2 * N_ + n];
        px2[p] = (v2f){x, x}; py2[p] = (v2f){y, y}; pz2[p] = (v2f){z, z};
        acx[p] = (v2f){0.f, 0.f}; acy[p] = (v2f){0.f, 0.f};
        acz[p] = (v2f){0.f, 0.f}; acw[p] = (v2f){0.f, 0.f};
    }

    const v2f t12 = (v2f){T1, T1}, t22 = (v2f){T2, T2};
    const v2f t32 = (v2f){T3, T3}, t42 = (v2f){T4, T4};
    const v2f one2 = (v2f){1.0f, 1.0f}, mone2 = (v2f){-1.0f, -1.0f};
    const v2f cbig2 = (v2f){RINT_C, RINT_C}, cneg2 = (v2f){-RINT_C, -RINT_C};

    // ---- main loop: pk poly-exp2 over sparse pairs ----
#pragma unroll 2
    for (int tp = 0; tp < TP; ++tp) {
        const float4 a1 = AXY[tp];     // broadcast ds_read_b128
        const float4 a2 = AZW[tp];
        const float4 f1 = FXY[tp];
        const v2f    fz2 = FZ2[tp];
        const v2f ax2 = (v2f){a1.x, a1.y}, ay2 = (v2f){a1.z, a1.w};
        const v2f az2 = (v2f){a2.x, a2.y}, bi2 = (v2f){a2.z, a2.w};
        const v2f fx2 = (v2f){f1.x, f1.y}, fy2 = (v2f){f1.z, f1.w};
#pragma unroll
        for (int p = 0; p < PPT; ++p) {
            v2f e2, t2, fl2, f2, pp, k2;
            PK_FMA(e2, pz2[p], az2, bi2);
            PK_FMA_ACC(e2, py2[p], ay2);
            PK_FMA_ACC(e2, px2[p], ax2);
            PK_ADD(t2, e2, cbig2);           // t = e + C  (rint trick)
            PK_ADD(fl2, t2, cneg2);          // fl = rint(e)
            PK_FMA(f2, fl2, mone2, e2);      // f = e - fl, in [-0.5, 0.5]
            PK_FMA(pp, t42, f2, t32);
            PK_HORNER(pp, f2, t22);
            PK_HORNER(pp, f2, t12);
            PK_FMA(k2, pp, f2, one2);        // 1 + f*P(f)
            const int i0 = __float_as_int(t2.x) - RINT_I;
            const int i1 = __float_as_int(t2.y) - RINT_I;
            v2f kk;
            kk.x = ldexpf(k2.x, i0);         // v_ldexp_f32
            kk.y = ldexpf(k2.y, i1);
            PK_FMA_ACC(acx[p], kk, fx2);
            PK_FMA_ACC(acy[p], kk, fy2);
            PK_FMA_ACC(acz[p], kk, fz2);
            PK_ADD_ACC(acw[p], kk);
        }
    }

    // ---- reduce s-halves, write partials (coalesced float4) ----
#pragma unroll
    for (int p = 0; p < PPT; ++p) {
        const int g = b * N_ + n0 + threadIdx.x + p * BLOCK;
        part[(size_t)sc * BN + g] = make_float4(
            acx[p].x + acx[p].y, acy[p].x + acy[p].y,
            acz[p].x + acz[p].y, acw[p].x + acw[p].y);
    }
}

__global__ __launch_bounds__(BLOCK) void uf2_combine(
    const float4* __restrict__ part, float* __restrict__ out, int SC)
{
    const int g = blockIdx.x * BLOCK + threadIdx.x;   // 0..BN-1
    float4 s0 = make_float4(0.f, 0.f, 0.f, 0.f);
    float4 s1 = s0, s2 = s0, s3 = s0;
    int c = 0;
    for (; c + 4 <= SC; c += 4) {
        const float4 p0 = part[(size_t)(c + 0) * BN + g];
        const float4 p1 = part[(size_t)(c + 1) * BN + g];
        const float4 p2 = part[(size_t)(c + 2) * BN + g];
        const float4 p3 = part[(size_t)(c + 3) * BN + g];
        s0.x += p0.x; s0.y += p0.y; s0.z += p0.z; s0.w += p0.w;
        s1.x += p1.x; s1.y += p1.y; s1.z += p1.z; s1.w += p1.w;
        s2.x += p2.x; s2.y += p2.y; s2.z += p2.z; s2.w += p2.w;
        s3.x += p3.x; s3.y += p3.y; s3.z += p3.z; s3.w += p3.w;
    }
    for (; c < SC; ++c) {
        const float4 p = part[(size_t)c * BN + g];
        s0.x += p.x; s0.y += p.y; s0.z += p.z; s0.w += p.w;
    }
    const float sx = (s0.x + s1.x) + (s2.x + s3.x);
    const float sy = (s0.y + s1.y) + (s2.y + s3.y);
    const float sz = (s0.z + s1.z) + (s2.z + s3.z);
    const float sw = (s0.w + s1.w) + (s2.w + s3.w);
    const float inv = 1.0f / sw;
    const int b = g >> 13;            // /8192
    const int n = g & (N_ - 1);
    float* ob = out + b * 3 * N_;
    ob[n]          = sx * inv;
    ob[N_ + n]     = sy * inv;
    ob[2 * N_ + n] = sz * inv;
}

// Fallback (ws too small): single kernel, full S staged in LDS, direct out.
__global__ __launch_bounds__(BLOCK, 1) void uf2_fused(
    const float* __restrict__ xyz,
    const float* __restrict__ sxyz,
    const float* __restrict__ sflow,
    const int* __restrict__ resol,
    float* __restrict__ out)
{
    constexpr int FPPT = 4;
    constexpr int PTS = BLOCK * FPPT;
    __shared__ float4 As[S_];
    __shared__ float4 Fs[S_];

    const int nb = blockIdx.x;
    const int b  = nb / (N_ / PTS);
    const int n0 = (nb % (N_ / PTS)) * PTS;

    const float r = (float)resol[0];
    const float inv_r2 = 1.0f / (r * r);
    const float c2 = 2.0f * inv_r2 * LOG2E;
    const float cy = -inv_r2 * LOG2E;

    const float* yb = sxyz  + b * 3 * S_;
    const float* fb = sflow + b * 3 * S_;
    for (int t = threadIdx.x; t < S_; t += BLOCK) {
        const float yx = yb[t], yy = yb[S_ + t], yz = yb[2 * S_ + t];
        const float fx = fb[t], fy = fb[S_ + t], fz = fb[2 * S_ + t];
        As[t] = make_float4(c2 * yx, c2 * yy, c2 * yz,
                            cy * (yx * yx + yy * yy + yz * yz));
        Fs[t] = make_float4(fx, fy, fz, 0.0f);
    }
    __syncthreads();

    const float* xb = xyz + b * 3 * N_;
    float px[FPPT], py[FPPT], pz[FPPT];
    float4 acc[FPPT];
#pragma unroll
    for (int p = 0; p < FPPT; ++p) {
        const int n = n0 + threadIdx.x + p * BLOCK;
        px[p] = xb[n]; py[p] = xb[N_ + n]; pz[p] = xb[2 * N_ + n];
        acc[p] = make_float4(0.f, 0.f, 0.f, 0.f);
    }
#pragma unroll 4
    for (int t = 0; t < S_; ++t) {
        const float4 a = As[t];
        const float4 f = Fs[t];
#pragma unroll
        for (int p = 0; p < FPPT; ++p) {
            float e = fmaf(pz[p], a.z, a.w);
            e = fmaf(py[p], a.y, e);
            e = fmaf(px[p], a.x, e);
            const float k = __builtin_amdgcn_exp2f(e);
            acc[p].x = fmaf(k, f.x, acc[p].x);
            acc[p].y = fmaf(k, f.y, acc[p].y);
            acc[p].z = fmaf(k, f.z, acc[p].z);
            acc[p].w += k;
        }
    }
#pragma unroll
    for (int p = 0; p < FPPT; ++p) {
        const int n = n0 + threadIdx.x + p * BLOCK;
        const float inv = 1.0f / acc[p].w;
        float* ob = out + b * 3 * N_;
        ob[n]          = acc[p].x * inv;
        ob[N_ + n]     = acc[p].y * inv;
        ob[2 * N_ + n] = acc[p].z * inv;
    }
}

extern "C" void kernel_launch(void* const* d_in, const int* in_sizes, int n_in,
                              void* d_out, int out_size, void* d_ws, size_t ws_size,
                              hipStream_t stream)
{
    const float* xyz   = (const float*)d_in[0];
    const float* sxyz  = (const float*)d_in[1];
    const float* sflow = (const float*)d_in[2];
    const int*   resol = (const int*)d_in[3];
    float* out = (float*)d_out;
    float4* part = (float4*)d_ws;

    const size_t per_chunk = (size_t)BN * sizeof(float4);   // 512 KB
    int SC = 16;
    while (SC > 1 && (size_t)SC * per_chunk > ws_size) SC >>= 1;

    if ((size_t)SC * per_chunk > ws_size) {
        uf2_fused<<<dim3(BN / 1024), dim3(BLOCK), 0, stream>>>(
            xyz, sxyz, sflow, resol, out);
        return;
    }

    dim3 grid(NB * SC), blk(BLOCK);
    switch (SC) {
        case 16: uf2_main<S_ / 16><<<grid, blk, 0, stream>>>(xyz, sxyz, sflow, resol, part); break;
        case 8:  uf2_main<S_ / 8 ><<<grid, blk, 0, stream>>>(xyz, sxyz, sflow, resol, part); break;
        case 4:  uf2_main<S_ / 4 ><<<grid, blk, 0, stream>>>(xyz, sxyz, sflow, resol, part); break;
        case 2:  uf2_main<S_ / 2 ><<<grid, blk, 0, stream>>>(xyz, sxyz, sflow, resol, part); break;
        default: uf2_main<S_     ><<<grid, blk, 0, stream>>>(xyz, sxyz, sflow, resol, part); break;
    }
    uf2_combine<<<dim3(BN / BLOCK), dim3(BLOCK), 0, stream>>>(part, out, SC);
}

// Round 14
// 31.049 us; speedup vs baseline: 2.5657x; 1.2763x over previous
//
#include <hip/hip_runtime.h>

// UpsampleFlow2: Gaussian Nadaraya-Watson upsampling.
// out [B,3,N] = (sum_s k*f)/(sum_s k), k = exp(-|x-y|^2/r^2).
// exp(-|x|^2/r^2) cancels in num/den ->
//   k' = exp2( fma(px,ax, fma(py,ay, fma(pz,az, bias))) )
//   a = c2*y, bias = cy*|y|^2, c2=2*log2e/r^2, cy=-log2e/r^2.
//
// R14: pk inner (R9, validated) x minimal-traffic geometry (R8, validated).
// Cross-round model (totals only; rocprof rows include replay overhead):
//   total = inner*tax + stage 2.5 + 0.155*SC + (0.08*SC+2) + fixed 11.5
// R9's pk halved fma issue (21.6 vs 28.6 cyc/pair) but its SC=32 traffic
// masked the win; R13's poly refuted the exp-replacement path (latency).
// Here: PPT=8 (NQ=4 v2f query pairs), SC=16, 256 blocks, bounds(256,2)
// (R12 lesson: never cap VGPR below footprint; est ~115 <= 128).
// exp stays hw v_exp_f32 (14.6 cyc/wave measured, irreplaceable).

typedef float v2f __attribute__((ext_vector_type(2)));

constexpr int B_ = 4, N_ = 8192, S_ = 2048;
constexpr int BLOCK = 256, PPT = 8, NQ = PPT / 2;   // 4 query pairs
constexpr int PTS_PER_BLOCK = BLOCK * PPT;      // 2048
constexpr int NBPB = N_ / PTS_PER_BLOCK;        // 4
constexpr int NB = B_ * NBPB;                   // 16
constexpr int BN = B_ * N_;                     // 32768
constexpr float LOG2E = 1.4426950408889634f;

#define PK_FMA(d, a, b, c) \
    asm("v_pk_fma_f32 %0, %1, %2, %3" : "=v"(d) : "v"(a), "v"(b), "v"(c))
#define PK_FMA_ACC(acc, a, b) \
    asm("v_pk_fma_f32 %0, %1, %2, %0" : "+v"(acc) : "v"(a), "v"(b))
#define PK_ADD_ACC(acc, a) \
    asm("v_pk_add_f32 %0, %1, %0" : "+v"(acc) : "v"(a))

template <int CHUNK>
__global__ __launch_bounds__(BLOCK, 2) void uf2_main(
    const float* __restrict__ xyz,
    const float* __restrict__ sxyz,
    const float* __restrict__ sflow,
    const int* __restrict__ resol,
    float4* __restrict__ part)
{
    __shared__ float4 A1[CHUNK];   // (ax, ax, ay, ay)
    __shared__ float4 A2[CHUNK];   // (az, az, bias, bias)
    __shared__ float4 F1[CHUNK];   // (fx, fx, fy, fy)
    __shared__ v2f    F2[CHUNK];   // (fz, fz)

    const int nb = blockIdx.x % NB;
    const int sc = blockIdx.x / NB;
    const int b  = nb / NBPB;
    const int n0 = (nb % NBPB) * PTS_PER_BLOCK;
    const int s0 = sc * CHUNK;

    const float r = (float)resol[0];            // INITIAL_RADIUS(=1)*resol
    const float inv_r2 = 1.0f / (r * r);
    const float c2 = 2.0f * inv_r2 * LOG2E;
    const float cy = -inv_r2 * LOG2E;

    // ---- stage sparse chunk, pre-splatted for pk consumption ----
    const float* yb = sxyz  + b * 3 * S_;
    const float* fb = sflow + b * 3 * S_;
    for (int t = threadIdx.x; t < CHUNK; t += BLOCK) {
        const int s = s0 + t;
        const float yx = yb[s], yy = yb[S_ + s], yz = yb[2 * S_ + s];
        const float fx = fb[s], fy = fb[S_ + s], fz = fb[2 * S_ + s];
        const float ax = c2 * yx, ay = c2 * yy, az = c2 * yz;
        const float bias = cy * (yx * yx + yy * yy + yz * yz);
        A1[t] = make_float4(ax, ax, ay, ay);
        A2[t] = make_float4(az, az, bias, bias);
        F1[t] = make_float4(fx, fx, fy, fy);
        F2[t] = (v2f){fz, fz};
    }
    __syncthreads();

    // ---- per-thread query points as v2f pairs ----
    const float* xb = xyz + b * 3 * N_;
    v2f px2[NQ], py2[NQ], pz2[NQ];
    v2f acx[NQ], acy[NQ], acz[NQ], acw[NQ];
#pragma unroll
    for (int q = 0; q < NQ; ++q) {
        const int na = n0 + threadIdx.x + (2 * q) * BLOCK;
        const int nc = na + BLOCK;
        px2[q] = (v2f){xb[na], xb[nc]};
        py2[q] = (v2f){xb[N_ + na], xb[N_ + nc]};
        pz2[q] = (v2f){xb[2 * N_ + na], xb[2 * N_ + nc]};
        acx[q] = (v2f){0.f, 0.f}; acy[q] = (v2f){0.f, 0.f};
        acz[q] = (v2f){0.f, 0.f}; acw[q] = (v2f){0.f, 0.f};
    }

    // ---- main loop: 3 b128 + 1 b64 broadcast reads; pk math per t ----
#pragma unroll 2
    for (int t = 0; t < CHUNK; ++t) {
        const float4 a1 = A1[t];           // broadcast ds_read_b128
        const float4 a2 = A2[t];
        const float4 f1 = F1[t];
        const v2f    fz2 = F2[t];
        const v2f ax2 = (v2f){a1.x, a1.y}, ay2 = (v2f){a1.z, a1.w};
        const v2f az2 = (v2f){a2.x, a2.y}, bi2 = (v2f){a2.z, a2.w};
        const v2f fx2 = (v2f){f1.x, f1.y}, fy2 = (v2f){f1.z, f1.w};
#pragma unroll
        for (int q = 0; q < NQ; ++q) {
            v2f e2;
            PK_FMA(e2, pz2[q], az2, bi2);
            PK_FMA_ACC(e2, py2[q], ay2);
            PK_FMA_ACC(e2, px2[q], ax2);
            v2f k2;
            k2.x = __builtin_amdgcn_exp2f(e2.x);
            k2.y = __builtin_amdgcn_exp2f(e2.y);
            PK_FMA_ACC(acx[q], k2, fx2);
            PK_FMA_ACC(acy[q], k2, fy2);
            PK_FMA_ACC(acz[q], k2, fz2);
            PK_ADD_ACC(acw[q], k2);
        }
    }

    // ---- write partials (coalesced float4) ----
#pragma unroll
    for (int q = 0; q < NQ; ++q) {
        const int ga = b * N_ + n0 + threadIdx.x + (2 * q) * BLOCK;
        part[(size_t)sc * BN + ga] =
            make_float4(acx[q].x, acy[q].x, acz[q].x, acw[q].x);
        part[(size_t)sc * BN + ga + BLOCK] =
            make_float4(acx[q].y, acy[q].y, acz[q].y, acw[q].y);
    }
}

__global__ __launch_bounds__(BLOCK) void uf2_combine(
    const float4* __restrict__ part, float* __restrict__ out, int SC)
{
    const int g = blockIdx.x * BLOCK + threadIdx.x;   // 0..BN-1
    float4 s0 = make_float4(0.f, 0.f, 0.f, 0.f);
    float4 s1 = s0, s2 = s0, s3 = s0;
    int c = 0;
    for (; c + 4 <= SC; c += 4) {
        const float4 p0 = part[(size_t)(c + 0) * BN + g];
        const float4 p1 = part[(size_t)(c + 1) * BN + g];
        const float4 p2 = part[(size_t)(c + 2) * BN + g];
        const float4 p3 = part[(size_t)(c + 3) * BN + g];
        s0.x += p0.x; s0.y += p0.y; s0.z += p0.z; s0.w += p0.w;
        s1.x += p1.x; s1.y += p1.y; s1.z += p1.z; s1.w += p1.w;
        s2.x += p2.x; s2.y += p2.y; s2.z += p2.z; s2.w += p2.w;
        s3.x += p3.x; s3.y += p3.y; s3.z += p3.z; s3.w += p3.w;
    }
    for (; c < SC; ++c) {
        const float4 p = part[(size_t)c * BN + g];
        s0.x += p.x; s0.y += p.y; s0.z += p.z; s0.w += p.w;
    }
    const float sx = (s0.x + s1.x) + (s2.x + s3.x);
    const float sy = (s0.y + s1.y) + (s2.y + s3.y);
    const float sz = (s0.z + s1.z) + (s2.z + s3.z);
    const float sw = (s0.w + s1.w) + (s2.w + s3.w);
    const float inv = 1.0f / sw;
    const int b = g >> 13;            // /8192
    const int n = g & (N_ - 1);
    float* ob = out + b * 3 * N_;
    ob[n]          = sx * inv;
    ob[N_ + n]     = sy * inv;
    ob[2 * N_ + n] = sz * inv;
}

// Fallback (ws too small): single kernel, full S staged in LDS, direct out.
__global__ __launch_bounds__(BLOCK, 1) void uf2_fused(
    const float* __restrict__ xyz,
    const float* __restrict__ sxyz,
    const float* __restrict__ sflow,
    const int* __restrict__ resol,
    float* __restrict__ out)
{
    constexpr int FPPT = 4;
    constexpr int PTS = BLOCK * FPPT;
    __shared__ float4 As[S_];
    __shared__ float4 Fs[S_];

    const int nb = blockIdx.x;
    const int b  = nb / (N_ / PTS);
    const int n0 = (nb % (N_ / PTS)) * PTS;

    const float r = (float)resol[0];
    const float inv_r2 = 1.0f / (r * r);
    const float c2 = 2.0f * inv_r2 * LOG2E;
    const float cy = -inv_r2 * LOG2E;

    const float* yb = sxyz  + b * 3 * S_;
    const float* fb = sflow + b * 3 * S_;
    for (int t = threadIdx.x; t < S_; t += BLOCK) {
        const float yx = yb[t], yy = yb[S_ + t], yz = yb[2 * S_ + t];
        const float fx = fb[t], fy = fb[S_ + t], fz = fb[2 * S_ + t];
        As[t] = make_float4(c2 * yx, c2 * yy, c2 * yz,
                            cy * (yx * yx + yy * yy + yz * yz));
        Fs[t] = make_float4(fx, fy, fz, 0.0f);
    }
    __syncthreads();

    const float* xb = xyz + b * 3 * N_;
    float px[FPPT], py[FPPT], pz[FPPT];
    float4 acc[FPPT];
#pragma unroll
    for (int p = 0; p < FPPT; ++p) {
        const int n = n0 + threadIdx.x + p * BLOCK;
        px[p] = xb[n]; py[p] = xb[N_ + n]; pz[p] = xb[2 * N_ + n];
        acc[p] = make_float4(0.f, 0.f, 0.f, 0.f);
    }
#pragma unroll 4
    for (int t = 0; t < S_; ++t) {
        const float4 a = As[t];
        const float4 f = Fs[t];
#pragma unroll
        for (int p = 0; p < FPPT; ++p) {
            float e = fmaf(pz[p], a.z, a.w);
            e = fmaf(py[p], a.y, e);
            e = fmaf(px[p], a.x, e);
            const float k = __builtin_amdgcn_exp2f(e);
            acc[p].x = fmaf(k, f.x, acc[p].x);
            acc[p].y = fmaf(k, f.y, acc[p].y);
            acc[p].z = fmaf(k, f.z, acc[p].z);
            acc[p].w += k;
        }
    }
#pragma unroll
    for (int p = 0; p < FPPT; ++p) {
        const int n = n0 + threadIdx.x + p * BLOCK;
        const float inv = 1.0f / acc[p].w;
        float* ob = out + b * 3 * N_;
        ob[n]          = acc[p].x * inv;
        ob[N_ + n]     = acc[p].y * inv;
        ob[2 * N_ + n] = acc[p].z * inv;
    }
}

extern "C" void kernel_launch(void* const* d_in, const int* in_sizes, int n_in,
                              void* d_out, int out_size, void* d_ws, size_t ws_size,
                              hipStream_t stream)
{
    const float* xyz   = (const float*)d_in[0];
    const float* sxyz  = (const float*)d_in[1];
    const float* sflow = (const float*)d_in[2];
    const int*   resol = (const int*)d_in[3];
    float* out = (float*)d_out;
    float4* part = (float4*)d_ws;

    const size_t per_chunk = (size_t)BN * sizeof(float4);   // 512 KB
    int SC = 16;
    while (SC > 1 && (size_t)SC * per_chunk > ws_size) SC >>= 1;

    if ((size_t)SC * per_chunk > ws_size) {
        uf2_fused<<<dim3(BN / 1024), dim3(BLOCK), 0, stream>>>(
            xyz, sxyz, sflow, resol, out);
        return;
    }

    dim3 grid(NB * SC), blk(BLOCK);
    switch (SC) {
        case 16: uf2_main<S_ / 16><<<grid, blk, 0, stream>>>(xyz, sxyz, sflow, resol, part); break;
        case 8:  uf2_main<S_ / 8 ><<<grid, blk, 0, stream>>>(xyz, sxyz, sflow, resol, part); break;
        case 4:  uf2_main<S_ / 4 ><<<grid, blk, 0, stream>>>(xyz, sxyz, sflow, resol, part); break;
        case 2:  uf2_main<S_ / 2 ><<<grid, blk, 0, stream>>>(xyz, sxyz, sflow, resol, part); break;
        default: uf2_main<S_     ><<<grid, blk, 0, stream>>>(xyz, sxyz, sflow, resol, part); break;
    }
    uf2_combine<<<dim3(BN / BLOCK), dim3(BLOCK), 0, stream>>>(part, out, SC);
}